// Round 1
// baseline (635.517 us; speedup 1.0000x reference)
//
#include <hip/hip_runtime.h>
#include <hip/hip_bf16.h>
#include <math.h>

// Problem constants (fixed by the reference)
#define B_    2
#define N_    120000
#define S_    40000
#define M_    30000
#define V_    100000
#define H_    256
#define WD_   1024
#define HID_  128
#define NSC_  4
#define NCLS_ 20
#define BM_   60000    // B*M rows of the image branch
#define BS_   80000    // B*S sample rows
#define BN_   240000   // B*N point rows

typedef __attribute__((ext_vector_type(8))) short bfrag8;   // 8 bf16 (4 VGPRs) MFMA A/B frag
typedef __attribute__((ext_vector_type(4))) float facc4;    // 4 f32 MFMA C/D frag

__device__ __forceinline__ unsigned short f2bf(float f){
  unsigned u = __builtin_bit_cast(unsigned, f);
  u += 0x7fffu + ((u >> 16) & 1u);          // round-to-nearest-even
  return (unsigned short)(u >> 16);
}
__device__ __forceinline__ float bf2f(unsigned short s){
  return __builtin_bit_cast(float, ((unsigned)s) << 16);
}

// ---------------------------------------------------------------------------
// Winner scatters: last-wins == max index (np assignment semantics).
__global__ __launch_bounds__(256) void k_winners(const int* __restrict__ p2i,
    const int* __restrict__ si, const int* __restrict__ ci,
    int* __restrict__ win_p, int* __restrict__ win_s, int* __restrict__ win_c){
  int t = blockIdx.x * 256 + threadIdx.x;
  if (t < BM_) atomicMax(&win_p[(t / M_) * N_ + p2i[t]], t);
  if (t < BS_) atomicMax(&win_s[(t / S_) * N_ + si[t]], t);
  if (t < BN_) atomicMax(&win_c[ci[t]], t);
}

// g_idx[row] = win_c[ci[b*N + p2i[row]]]  (always >= 0: row itself scattered there)
__global__ __launch_bounds__(256) void k_gidx(const int* __restrict__ p2i,
    const int* __restrict__ ci, const int* __restrict__ win_c, int* __restrict__ gidx){
  int t = blockIdx.x * 256 + threadIdx.x;
  if (t >= BM_) return;
  int j = (t / M_) * N_ + p2i[t];
  gidx[t] = win_c[ci[j]];
}

// img_at_pts[row][h] = img_latent[b][h][r][c]   (scattered 4B reads, coalesced writes)
__global__ __launch_bounds__(256) void k_imggather(const float* __restrict__ img,
    const int* __restrict__ ptsimg, float* __restrict__ iap){
  int t = blockIdx.x * 256 + threadIdx.x;       // t = row*128 + h, exact grid
  int row = t >> 7, h = t & 127;
  int b = row / M_;
  int r = ptsimg[row * 2 + 0];
  int c = ptsimg[row * 2 + 1];
  iap[t] = img[(((size_t)b * HID_ + h) * H_ + r) * WD_ + c];
}

// output_3d[j][i*128 + c] = samp_i[win_s[j]][c] + img_at_pts[win_p[j]][c]
__global__ __launch_bounds__(256) void k_out3d(const float* __restrict__ samp,
    const int* __restrict__ win_s, const int* __restrict__ win_p,
    const float* __restrict__ iap, float* __restrict__ o3d){
  int t = blockIdx.x * 256 + threadIdx.x;       // t = j*32 + q (float4 lane), exact grid
  int j = t >> 5, q = t & 31;
  int sj = win_s[j], pj = win_p[j];
  float4 iv = {0.f, 0.f, 0.f, 0.f};
  if (pj >= 0) iv = *(const float4*)(iap + (size_t)pj * HID_ + q * 4);
  #pragma unroll
  for (int i = 0; i < NSC_; i++){
    float4 v = iv;
    if (sj >= 0){
      float4 s = *(const float4*)(samp + ((size_t)i * BS_ + sj) * HID_ + q * 4);
      v.x += s.x; v.y += s.y; v.z += s.z; v.w += s.w;
    }
    *(float4*)(o3d + (size_t)j * (NSC_ * HID_) + i * HID_ + q * 4) = v;
  }
}

// Pre-transpose all GEMM weights to bf16 [n][k] layout (ws), so B-frags are
// contiguous ds_read_b128 after LDS staging.
__global__ __launch_bounds__(256) void k_prep(const float* __restrict__ lW,
    const float* __restrict__ f1W, const float* __restrict__ f2W,
    const float* __restrict__ c1W, unsigned short* __restrict__ lwT,
    unsigned short* __restrict__ f1T, unsigned short* __restrict__ f2T,
    unsigned short* __restrict__ c1T){
  int t = blockIdx.x * 256 + threadIdx.x;       // 327680 exact
  if (t < 65536){                                // leaner: 4 x [128][128]
    int i = t >> 14, r = t & 16383, n = r >> 7, k = r & 127;
    lwT[i * 16384 + n * 128 + k] = f2bf(lW[i * 16384 + k * 128 + n]);
  } else if (t < 196608){                        // fcs1: 4 x [128][256]
    int e = t - 65536;
    int i = e >> 15, r = e & 32767, n = r >> 8, k = r & 255;
    f1T[i * 32768 + n * 256 + k] = f2bf(f1W[i * 32768 + k * 128 + n]);
  } else if (t < 262144){                        // fcs2: 4 x [128][128]
    int e = t - 196608;
    int i = e >> 14, r = e & 16383, n = r >> 7, k = r & 127;
    f2T[i * 16384 + n * 128 + k] = f2bf(f2W[i * 16384 + k * 128 + n]);
  } else {                                       // cls_W1: [128][512]
    int e = t - 262144;
    int n = e >> 9, k = e & 511;
    c1T[n * 512 + k] = f2bf(c1W[k * 128 + n]);
  }
}

// ---------------------------------------------------------------------------
// MFMA GEMM kernels. Block = 256 threads (4 waves), tile 64 rows x 128 cols.
// Wave w owns rows [blk*64 + w*16, +16). A frag: row = lane&15, k = (lane>>4)*8+e.
// B frag from swizzled LDS Wt[n][k]: col = lane&15 (+16*ct). D: col=lane&15,
// row=(lane>>4)*4+reg  [m89-verified].

// leaner: fl = relu(gathered_sp @ Wl + bl)
__global__ __launch_bounds__(256) void k_leaner(int i, const float* __restrict__ samp,
    const float* __restrict__ iap, const int* __restrict__ gidx,
    const int* __restrict__ win_s, const int* __restrict__ win_p,
    const unsigned short* __restrict__ lwT, const float* __restrict__ lb,
    unsigned short* __restrict__ fl){
  __shared__ char lds[32768];                    // Wt [128][128] bf16, XOR-swizzled
  {
    const char* src = (const char*)(lwT + (size_t)i * 16384);
    for (int c = threadIdx.x; c < 2048; c += 256){
      int byte = c << 4; int n = byte >> 8;
      *(bfrag8*)(lds + (byte ^ ((n & 7) << 4))) = *(const bfrag8*)(src + byte);
    }
  }
  __syncthreads();
  const int lane = threadIdx.x & 63, wv = threadIdx.x >> 6;
  const int rl = lane & 15, kg = lane >> 4;
  const int rowBase = blockIdx.x * 64 + wv * 16;
  int row = rowBase + rl;
  bool rv = row < BM_;
  int gj = rv ? gidx[row] : 0;
  int sj = rv ? win_s[gj] : -1;
  int pj = rv ? win_p[gj] : -1;
  const float* sp = samp + ((size_t)i * BS_ + (sj < 0 ? 0 : sj)) * HID_;
  const float* pp = iap + (size_t)(pj < 0 ? 0 : pj) * HID_;
  facc4 acc[8];
  #pragma unroll
  for (int ct = 0; ct < 8; ct++) acc[ct] = (facc4){0.f, 0.f, 0.f, 0.f};
  #pragma unroll
  for (int kc = 0; kc < 4; kc++){
    int k0 = kc * 32 + kg * 8;
    bfrag8 a;
    #pragma unroll
    for (int e = 0; e < 8; e += 4){
      float4 s = {0.f,0.f,0.f,0.f}, g = {0.f,0.f,0.f,0.f};
      if (sj >= 0) s = *(const float4*)(sp + k0 + e);
      if (pj >= 0) g = *(const float4*)(pp + k0 + e);
      a[e+0] = (short)f2bf(s.x + g.x); a[e+1] = (short)f2bf(s.y + g.y);
      a[e+2] = (short)f2bf(s.z + g.z); a[e+3] = (short)f2bf(s.w + g.w);
    }
    #pragma unroll
    for (int ct = 0; ct < 8; ct++){
      int col = ct * 16 + rl;
      int byte = (col << 8) + (k0 << 1);
      bfrag8 b = *(const bfrag8*)(lds + (byte ^ ((col & 7) << 4)));
      acc[ct] = __builtin_amdgcn_mfma_f32_16x16x32_bf16(a, b, acc[ct], 0, 0, 0);
    }
  }
  const float* bias = lb + i * HID_;
  #pragma unroll
  for (int ct = 0; ct < 8; ct++){
    int col = ct * 16 + rl;
    float bv = bias[col];
    #pragma unroll
    for (int r = 0; r < 4; r++){
      int orow = rowBase + kg * 4 + r;
      if (orow < BM_){
        float v = acc[ct][r] + bv;
        v = v > 0.f ? v : 0.f;
        fl[(size_t)orow * HID_ + col] = f2bf(v);
      }
    }
  }
}

// fcs1: fc = [img_feat | fl] @ W1 + b1   (K=256, no activation)
__global__ __launch_bounds__(256) void k_fcs1(int i, const float* __restrict__ imgf,
    const unsigned short* __restrict__ fl, const unsigned short* __restrict__ f1T,
    const float* __restrict__ f1b, unsigned short* __restrict__ fc){
  __shared__ char lds[65536];                    // Wt [128][256] bf16
  {
    const char* src = (const char*)(f1T + (size_t)i * 32768);
    for (int c = threadIdx.x; c < 4096; c += 256){
      int byte = c << 4; int n = byte >> 9;
      *(bfrag8*)(lds + (byte ^ ((n & 7) << 4))) = *(const bfrag8*)(src + byte);
    }
  }
  __syncthreads();
  const int lane = threadIdx.x & 63, wv = threadIdx.x >> 6;
  const int rl = lane & 15, kg = lane >> 4;
  const int rowBase = blockIdx.x * 64 + wv * 16;
  int row = rowBase + rl;
  bool rv = row < BM_;
  const float* a1 = imgf + ((size_t)i * BM_ + (rv ? row : 0)) * HID_;
  const unsigned short* a2 = fl + (size_t)(rv ? row : 0) * HID_;
  facc4 acc[8];
  #pragma unroll
  for (int ct = 0; ct < 8; ct++) acc[ct] = (facc4){0.f, 0.f, 0.f, 0.f};
  #pragma unroll
  for (int kc = 0; kc < 8; kc++){
    int kk = kc * 32 + kg * 8;
    bfrag8 a = (bfrag8){0,0,0,0,0,0,0,0};
    if (kc < 4){
      if (rv){
        float4 s0 = *(const float4*)(a1 + kk);
        float4 s1 = *(const float4*)(a1 + kk + 4);
        a[0]=(short)f2bf(s0.x); a[1]=(short)f2bf(s0.y); a[2]=(short)f2bf(s0.z); a[3]=(short)f2bf(s0.w);
        a[4]=(short)f2bf(s1.x); a[5]=(short)f2bf(s1.y); a[6]=(short)f2bf(s1.z); a[7]=(short)f2bf(s1.w);
      }
    } else {
      if (rv) a = *(const bfrag8*)(a2 + (kk - 128));
    }
    #pragma unroll
    for (int ct = 0; ct < 8; ct++){
      int col = ct * 16 + rl;
      int byte = (col << 9) + (kk << 1);
      bfrag8 b = *(const bfrag8*)(lds + (byte ^ ((col & 7) << 4)));
      acc[ct] = __builtin_amdgcn_mfma_f32_16x16x32_bf16(a, b, acc[ct], 0, 0, 0);
    }
  }
  const float* bias = f1b + i * HID_;
  #pragma unroll
  for (int ct = 0; ct < 8; ct++){
    int col = ct * 16 + rl;
    float bv = bias[col];
    #pragma unroll
    for (int r = 0; r < 4; r++){
      int orow = rowBase + kg * 4 + r;
      if (orow < BM_) fc[(size_t)orow * HID_ + col] = f2bf(acc[ct][r] + bv);
    }
  }
}

// fcs2 + fuse: seg[:, i*128:] = relu(fc * sigmoid(fc @ W2 + b2))
__global__ __launch_bounds__(256) void k_fcs2(int i, const unsigned short* __restrict__ fc,
    const unsigned short* __restrict__ f2T, const float* __restrict__ f2b,
    unsigned short* __restrict__ seg){
  __shared__ char lds[32768];
  {
    const char* src = (const char*)(f2T + (size_t)i * 16384);
    for (int c = threadIdx.x; c < 2048; c += 256){
      int byte = c << 4; int n = byte >> 8;
      *(bfrag8*)(lds + (byte ^ ((n & 7) << 4))) = *(const bfrag8*)(src + byte);
    }
  }
  __syncthreads();
  const int lane = threadIdx.x & 63, wv = threadIdx.x >> 6;
  const int rl = lane & 15, kg = lane >> 4;
  const int rowBase = blockIdx.x * 64 + wv * 16;
  int row = rowBase + rl;
  bool rv = row < BM_;
  const unsigned short* ar = fc + (size_t)(rv ? row : 0) * HID_;
  facc4 acc[8];
  #pragma unroll
  for (int ct = 0; ct < 8; ct++) acc[ct] = (facc4){0.f, 0.f, 0.f, 0.f};
  #pragma unroll
  for (int kc = 0; kc < 4; kc++){
    int kk = kc * 32 + kg * 8;
    bfrag8 a = (bfrag8){0,0,0,0,0,0,0,0};
    if (rv) a = *(const bfrag8*)(ar + kk);
    #pragma unroll
    for (int ct = 0; ct < 8; ct++){
      int col = ct * 16 + rl;
      int byte = (col << 8) + (kk << 1);
      bfrag8 b = *(const bfrag8*)(lds + (byte ^ ((col & 7) << 4)));
      acc[ct] = __builtin_amdgcn_mfma_f32_16x16x32_bf16(a, b, acc[ct], 0, 0, 0);
    }
  }
  const float* bias = f2b + i * HID_;
  #pragma unroll
  for (int ct = 0; ct < 8; ct++){
    int col = ct * 16 + rl;
    float bv = bias[col];
    #pragma unroll
    for (int r = 0; r < 4; r++){
      int orow = rowBase + kg * 4 + r;
      if (orow < BM_){
        float t = acc[ct][r] + bv;
        float fw = 1.f / (1.f + expf(-t));
        float fcv = bf2f(fc[(size_t)orow * HID_ + col]);
        float u = fcv * fw;
        u = u > 0.f ? u : 0.f;
        seg[(size_t)orow * (NSC_ * HID_) + i * HID_ + col] = f2bf(u);
      }
    }
  }
}

// cls1: hid = relu(seg @ cls_W1 + b1)  (K=512, two 64KB LDS phases)
__global__ __launch_bounds__(256) void k_cls1(const unsigned short* __restrict__ seg,
    const unsigned short* __restrict__ c1T, const float* __restrict__ c1b,
    unsigned short* __restrict__ hid){
  __shared__ char lds[65536];                    // half of Wt [128][512] per phase
  const int lane = threadIdx.x & 63, wv = threadIdx.x >> 6;
  const int rl = lane & 15, kg = lane >> 4;
  const int rowBase = blockIdx.x * 64 + wv * 16;
  int row = rowBase + rl;
  bool rv = row < BM_;
  const unsigned short* ar = seg + (size_t)(rv ? row : 0) * 512;
  facc4 acc[8];
  #pragma unroll
  for (int ct = 0; ct < 8; ct++) acc[ct] = (facc4){0.f, 0.f, 0.f, 0.f};
  for (int ph = 0; ph < 2; ph++){
    if (ph) __syncthreads();
    for (int c = threadIdx.x; c < 4096; c += 256){
      int byte = c << 4; int n = byte >> 9; int off = byte & 511;
      *(bfrag8*)(lds + (byte ^ ((n & 7) << 4))) =
          *(const bfrag8*)((const char*)c1T + (size_t)n * 1024 + ph * 512 + off);
    }
    __syncthreads();
    #pragma unroll
    for (int kc = 0; kc < 8; kc++){
      int kk = kc * 32 + kg * 8;
      bfrag8 a = (bfrag8){0,0,0,0,0,0,0,0};
      if (rv) a = *(const bfrag8*)(ar + ph * 256 + kk);
      #pragma unroll
      for (int ct = 0; ct < 8; ct++){
        int col = ct * 16 + rl;
        int byte = (col << 9) + (kk << 1);
        bfrag8 b = *(const bfrag8*)(lds + (byte ^ ((col & 7) << 4)));
        acc[ct] = __builtin_amdgcn_mfma_f32_16x16x32_bf16(a, b, acc[ct], 0, 0, 0);
      }
    }
  }
  #pragma unroll
  for (int ct = 0; ct < 8; ct++){
    int col = ct * 16 + rl;
    float bv = c1b[col];
    #pragma unroll
    for (int r = 0; r < 4; r++){
      int orow = rowBase + kg * 4 + r;
      if (orow < BM_){
        float v = acc[ct][r] + bv;
        v = v > 0.f ? v : 0.f;
        hid[(size_t)orow * HID_ + col] = f2bf(v);
      }
    }
  }
}

// cls2: logits = hid @ cls_W2 + b2  (N=20, tiny — plain fp32 dot)
__global__ __launch_bounds__(256) void k_cls2(const unsigned short* __restrict__ hid,
    const float* __restrict__ W2, const float* __restrict__ b2, float* __restrict__ out){
  int t = blockIdx.x * 256 + threadIdx.x;
  if (t >= BM_ * NCLS_) return;
  int row = t / NCLS_, n = t - row * NCLS_;
  const unsigned short* h = hid + (size_t)row * HID_;
  float acc = b2[n];
  #pragma unroll
  for (int k8 = 0; k8 < 16; k8++){
    bfrag8 hv = *(const bfrag8*)(h + k8 * 8);
    #pragma unroll
    for (int e = 0; e < 8; e++)
      acc += bf2f((unsigned short)hv[e]) * W2[(k8 * 8 + e) * NCLS_ + n];
  }
  out[t] = acc;
}

// ---------------------------------------------------------------------------
extern "C" void kernel_launch(void* const* d_in, const int* in_sizes, int n_in,
                              void* d_out, int out_size, void* d_ws, size_t ws_size,
                              hipStream_t stream){
  const float* samp = (const float*)d_in[1];   // pts_sample_feat (pts_feat_layers[0] is dead)
  const float* img  = (const float*)d_in[2];
  const float* imgf = (const float*)d_in[3];
  const float* lW   = (const float*)d_in[4];
  const float* lb   = (const float*)d_in[5];
  const float* f1W  = (const float*)d_in[6];
  const float* f1b  = (const float*)d_in[7];
  const float* f2W  = (const float*)d_in[8];
  const float* f2b  = (const float*)d_in[9];
  const float* c1W  = (const float*)d_in[10];
  const float* c1b  = (const float*)d_in[11];
  const float* c2W  = (const float*)d_in[12];
  const float* c2b  = (const float*)d_in[13];
  const int* ptsimg = (const int*)d_in[14];
  const int* p2i    = (const int*)d_in[15];
  const int* si     = (const int*)d_in[16];
  const int* ci     = (const int*)d_in[17];

  char* ws = (char*)d_ws;
  int*   win_p = (int*)(ws + 0);                       //   960,000 B
  int*   win_s = (int*)(ws + 960000);                  //   960,000 B
  int*   win_c = (int*)(ws + 1920000);                 //   400,000 B
  int*   gidx  = (int*)(ws + 2320128);                 //   240,000 B
  float* iap   = (float*)(ws + 2560256);               // 30,720,000 B
  unsigned short* fl  = (unsigned short*)(ws + 33280256);   // 15,360,000 B
  unsigned short* fc  = (unsigned short*)(ws + 48640256);   // 15,360,000 B
  unsigned short* seg = (unsigned short*)(ws + 64000256);   // 61,440,000 B
  unsigned short* lwT = (unsigned short*)(ws + 125440256);  // weights ~0.66 MB
  unsigned short* f1T = lwT + 65536;
  unsigned short* f2T = f1T + 131072;
  unsigned short* c1T = f2T + 65536;
  unsigned short* hid = fl;                            // alias: fl dead before cls1

  float* logits = (float*)d_out;
  float* o3d    = (float*)d_out + (size_t)BM_ * NCLS_;

  hipMemsetAsync(ws, 0xFF, 2320000, stream);           // win_* = -1
  k_winners  <<<938,   256, 0, stream>>>(p2i, si, ci, win_p, win_s, win_c);
  k_imggather<<<30000, 256, 0, stream>>>(img, ptsimg, iap);
  k_gidx     <<<235,   256, 0, stream>>>(p2i, ci, win_c, gidx);
  k_prep     <<<1280,  256, 0, stream>>>(lW, f1W, f2W, c1W, lwT, f1T, f2T, c1T);
  k_out3d    <<<30000, 256, 0, stream>>>(samp, win_s, win_p, iap, o3d);
  for (int i = 0; i < NSC_; i++){
    k_leaner<<<938, 256, 0, stream>>>(i, samp, iap, gidx, win_s, win_p, lwT, lb, fl);
    k_fcs1  <<<938, 256, 0, stream>>>(i, imgf, fl, f1T, f1b, fc);
    k_fcs2  <<<938, 256, 0, stream>>>(i, fc, f2T, f2b, seg);
  }
  k_cls1<<<938,  256, 0, stream>>>(seg, c1T, c1b, hid);
  k_cls2<<<4688, 256, 0, stream>>>(hid, c2W, c2b, logits);
}

// Round 3
// 558.058 us; speedup vs baseline: 1.1388x; 1.1388x over previous
//
#include <hip/hip_runtime.h>
#include <hip/hip_bf16.h>
#include <math.h>

// Problem constants (fixed by the reference)
#define B_    2
#define N_    120000
#define S_    40000
#define M_    30000
#define V_    100000
#define H_    256
#define WD_   1024
#define HID_  128
#define NSC_  4
#define NCLS_ 20
#define BM_   60000    // B*M rows of the image branch
#define BS_   80000    // B*S sample rows
#define BN_   240000   // B*N point rows

typedef __attribute__((ext_vector_type(8))) short bfrag8;   // 8 bf16 (4 VGPRs) MFMA A/B frag
typedef __attribute__((ext_vector_type(4))) float facc4;    // 4 f32 MFMA C/D frag (native vec)

__device__ __forceinline__ unsigned short f2bf(float f){
  unsigned u = __builtin_bit_cast(unsigned, f);
  u += 0x7fffu + ((u >> 16) & 1u);          // round-to-nearest-even
  return (unsigned short)(u >> 16);
}
__device__ __forceinline__ float bf2f(unsigned short s){
  return __builtin_bit_cast(float, ((unsigned)s) << 16);
}

// ---------------------------------------------------------------------------
// Winner scatters: last-wins == max index (np assignment semantics).
__global__ __launch_bounds__(256) void k_winners(const int* __restrict__ p2i,
    const int* __restrict__ si, const int* __restrict__ ci,
    int* __restrict__ win_p, int* __restrict__ win_s, int* __restrict__ win_c){
  int t = blockIdx.x * 256 + threadIdx.x;
  if (t < BM_) atomicMax(&win_p[(t / M_) * N_ + p2i[t]], t);
  if (t < BS_) atomicMax(&win_s[(t / S_) * N_ + si[t]], t);
  if (t < BN_) atomicMax(&win_c[ci[t]], t);
}

// g_idx[row] = win_c[ci[b*N + p2i[row]]]  (always >= 0: row itself scattered there)
__global__ __launch_bounds__(256) void k_gidx(const int* __restrict__ p2i,
    const int* __restrict__ ci, const int* __restrict__ win_c, int* __restrict__ gidx){
  int t = blockIdx.x * 256 + threadIdx.x;
  if (t >= BM_) return;
  int j = (t / M_) * N_ + p2i[t];
  gidx[t] = win_c[ci[j]];
}

// img_at_pts[row][h] = bf16(img_latent[b][h][r][c])  (scattered 4B reads)
__global__ __launch_bounds__(256) void k_imggather(const float* __restrict__ img,
    const int* __restrict__ ptsimg, unsigned short* __restrict__ iap){
  int t = blockIdx.x * 256 + threadIdx.x;       // t = row*128 + h, exact grid
  int row = t >> 7, h = t & 127;
  int b = row / M_;
  int r = ptsimg[row * 2 + 0];
  int c = ptsimg[row * 2 + 1];
  iap[t] = f2bf(img[(((size_t)b * HID_ + h) * H_ + r) * WD_ + c]);
}

// output_3d[j][i*128 + c] = samp_i[win_s[j]][c] + img_at_pts[win_p[j]][c]
__global__ __launch_bounds__(256) void k_out3d(const float* __restrict__ samp,
    const int* __restrict__ win_s, const int* __restrict__ win_p,
    const unsigned short* __restrict__ iap, float* __restrict__ o3d){
  int t = blockIdx.x * 256 + threadIdx.x;       // t = j*32 + q (float4 lane), exact grid
  int j = t >> 5, q = t & 31;
  int sj = win_s[j], pj = win_p[j];
  facc4 iv = {0.f, 0.f, 0.f, 0.f};
  if (pj >= 0){
    ushort4 u = *(const ushort4*)(iap + (size_t)pj * HID_ + q * 4);
    iv.x = bf2f(u.x); iv.y = bf2f(u.y); iv.z = bf2f(u.z); iv.w = bf2f(u.w);
  }
  #pragma unroll
  for (int i = 0; i < NSC_; i++){
    facc4 v = iv;
    if (sj >= 0){
      facc4 s = *(const facc4*)(samp + ((size_t)i * BS_ + sj) * HID_ + q * 4);
      v += s;
    }
    __builtin_nontemporal_store(v, (facc4*)(o3d + (size_t)j * (NSC_ * HID_) + i * HID_ + q * 4));
  }
}

// Pre-transpose all GEMM weights to bf16 [n][k] layout.
__global__ __launch_bounds__(256) void k_prep(const float* __restrict__ lW,
    const float* __restrict__ f1W, const float* __restrict__ f2W,
    const float* __restrict__ c1W, const float* __restrict__ c2W,
    unsigned short* __restrict__ lwT, unsigned short* __restrict__ f1T,
    unsigned short* __restrict__ f2T, unsigned short* __restrict__ c1T,
    unsigned short* __restrict__ c2T){
  int t = blockIdx.x * 256 + threadIdx.x;       // 330240 exact
  if (t < 65536){                                // leaner: 4 x [128][128]
    int i = t >> 14, r = t & 16383, n = r >> 7, k = r & 127;
    lwT[i * 16384 + n * 128 + k] = f2bf(lW[i * 16384 + k * 128 + n]);
  } else if (t < 196608){                        // fcs1: 4 x [128][256]
    int e = t - 65536;
    int i = e >> 15, r = e & 32767, n = r >> 8, k = r & 255;
    f1T[i * 32768 + n * 256 + k] = f2bf(f1W[i * 32768 + k * 128 + n]);
  } else if (t < 262144){                        // fcs2: 4 x [128][128]
    int e = t - 196608;
    int i = e >> 14, r = e & 16383, n = r >> 7, k = r & 127;
    f2T[i * 16384 + n * 128 + k] = f2bf(f2W[i * 16384 + k * 128 + n]);
  } else if (t < 327680){                        // cls_W1: [128][512]
    int e = t - 262144;
    int n = e >> 9, k = e & 511;
    c1T[n * 512 + k] = f2bf(c1W[k * 128 + n]);
  } else if (t < 330240){                        // cls_W2: [20][128]
    int e = t - 327680;
    int n = e >> 7, k = e & 127;
    c2T[n * 128 + k] = f2bf(c2W[k * NCLS_ + n]);
  }
}

// ---------------------------------------------------------------------------
// Fused per-scale MLP: seg[:, i*128:(i+1)*128] =
//   relu(fc * sigmoid(fc @ W2 + b2)),  fc = [imgf_i | relu(spG @ Wl + bl)] @ W1 + b1
// Block = 256 thr (4 waves), 64 rows. LDS: 64KB weight buf (re-staged per phase)
// + 16KB act buf (fl/fc round-trip D-layout -> A-frag). 2 blocks/CU.
__global__ __launch_bounds__(256) void k_scale(int i,
    const float* __restrict__ o3d, const int* __restrict__ gidx,
    const float* __restrict__ imgf,
    const unsigned short* __restrict__ lwT, const float* __restrict__ lb,
    const unsigned short* __restrict__ f1T, const float* __restrict__ f1b,
    const unsigned short* __restrict__ f2T, const float* __restrict__ f2b,
    unsigned short* __restrict__ seg){
  __shared__ char lds[81920];
  char* actL = lds + 65536;
  const int lane = threadIdx.x & 63, wv = threadIdx.x >> 6;
  const int rl = lane & 15, kg = lane >> 4;
  const int rowBase = blockIdx.x * 64 + wv * 16;
  const int row = rowBase + rl;                 // this lane's A row
  const bool rv = row < BM_;
  const int lr = wv * 16 + rl;                  // block-local A row

  // ---- Phase A: leaner ----
  {
    const char* src = (const char*)(lwT + (size_t)i * 16384);
    for (int c = threadIdx.x; c < 2048; c += 256){
      int byte = c << 4; int n = byte >> 8;
      *(bfrag8*)(lds + (byte ^ ((n & 7) << 4))) = *(const bfrag8*)(src + byte);
    }
  }
  bfrag8 afr[4];
  {
    const float* aA = o3d + (size_t)(rv ? gidx[row] : 0) * (NSC_ * HID_) + i * HID_;
    #pragma unroll
    for (int kc = 0; kc < 4; kc++){
      int k0 = kc * 32 + kg * 8;
      facc4 s0 = {0,0,0,0}, s1 = {0,0,0,0};
      if (rv){ s0 = *(const facc4*)(aA + k0); s1 = *(const facc4*)(aA + k0 + 4); }
      bfrag8 a;
      a[0]=(short)f2bf(s0.x); a[1]=(short)f2bf(s0.y); a[2]=(short)f2bf(s0.z); a[3]=(short)f2bf(s0.w);
      a[4]=(short)f2bf(s1.x); a[5]=(short)f2bf(s1.y); a[6]=(short)f2bf(s1.z); a[7]=(short)f2bf(s1.w);
      afr[kc] = a;
    }
  }
  __syncthreads();
  facc4 accL[8];
  #pragma unroll
  for (int ct = 0; ct < 8; ct++) accL[ct] = (facc4){0.f,0.f,0.f,0.f};
  #pragma unroll
  for (int kc = 0; kc < 4; kc++){
    int k0 = kc * 32 + kg * 8;
    #pragma unroll
    for (int ct = 0; ct < 8; ct++){
      int col = ct * 16 + rl;
      int byte = (col << 8) + (k0 << 1);
      bfrag8 b = *(const bfrag8*)(lds + (byte ^ ((col & 7) << 4)));
      accL[ct] = __builtin_amdgcn_mfma_f32_16x16x32_bf16(afr[kc], b, accL[ct], 0, 0, 0);
    }
  }
  __syncthreads();                               // all waves done with W + act free
  // fl -> act LDS (bf16, relu), stage fcs1 W
  {
    const float* bias = lb + i * HID_;
    #pragma unroll
    for (int ct = 0; ct < 8; ct++){
      int col = ct * 16 + rl;
      float bv = bias[col];
      #pragma unroll
      for (int r = 0; r < 4; r++){
        int ar = wv * 16 + kg * 4 + r;
        float v = accL[ct][r] + bv; v = v > 0.f ? v : 0.f;
        int byte = ar * 256 + col * 2;
        *(unsigned short*)(actL + (byte ^ ((ar & 7) << 4))) = f2bf(v);
      }
    }
    const char* src = (const char*)(f1T + (size_t)i * 32768);
    for (int c = threadIdx.x; c < 4096; c += 256){
      int byte = c << 4; int n = byte >> 9;
      *(bfrag8*)(lds + (byte ^ ((n & 7) << 4))) = *(const bfrag8*)(src + byte);
    }
  }
  __syncthreads();
  // ---- Phase B: fcs1 (K=256) ----
  facc4 accF[8];
  #pragma unroll
  for (int ct = 0; ct < 8; ct++) accF[ct] = (facc4){0.f,0.f,0.f,0.f};
  {
    const float* a1 = imgf + ((size_t)i * BM_ + (rv ? row : 0)) * HID_;
    #pragma unroll
    for (int kc = 0; kc < 8; kc++){
      int kk = kc * 32 + kg * 8;
      bfrag8 a;
      if (kc < 4){
        a = (bfrag8){0,0,0,0,0,0,0,0};
        if (rv){
          facc4 s0 = *(const facc4*)(a1 + kk);
          facc4 s1 = *(const facc4*)(a1 + kk + 4);
          a[0]=(short)f2bf(s0.x); a[1]=(short)f2bf(s0.y); a[2]=(short)f2bf(s0.z); a[3]=(short)f2bf(s0.w);
          a[4]=(short)f2bf(s1.x); a[5]=(short)f2bf(s1.y); a[6]=(short)f2bf(s1.z); a[7]=(short)f2bf(s1.w);
        }
      } else {
        int byte = lr * 256 + (kk - 128) * 2;
        a = *(const bfrag8*)(actL + (byte ^ ((lr & 7) << 4)));
      }
      #pragma unroll
      for (int ct = 0; ct < 8; ct++){
        int col = ct * 16 + rl;
        int byte = (col << 9) + (kk << 1);
        bfrag8 b = *(const bfrag8*)(lds + (byte ^ ((col & 7) << 4)));
        accF[ct] = __builtin_amdgcn_mfma_f32_16x16x32_bf16(a, b, accF[ct], 0, 0, 0);
      }
    }
  }
  __syncthreads();
  // fc (+bias, kept f32 in accF) -> act LDS, stage fcs2 W
  {
    const float* bias = f1b + i * HID_;
    #pragma unroll
    for (int ct = 0; ct < 8; ct++){
      int col = ct * 16 + rl;
      float bv = bias[col];
      #pragma unroll
      for (int r = 0; r < 4; r++){
        int ar = wv * 16 + kg * 4 + r;
        float v = accF[ct][r] + bv;
        accF[ct][r] = v;
        int byte = ar * 256 + col * 2;
        *(unsigned short*)(actL + (byte ^ ((ar & 7) << 4))) = f2bf(v);
      }
    }
    const char* src = (const char*)(f2T + (size_t)i * 16384);
    for (int c = threadIdx.x; c < 2048; c += 256){
      int byte = c << 4; int n = byte >> 8;
      *(bfrag8*)(lds + (byte ^ ((n & 7) << 4))) = *(const bfrag8*)(src + byte);
    }
  }
  __syncthreads();
  // ---- Phase C: fcs2 + gate epilogue ----
  facc4 accT[8];
  #pragma unroll
  for (int ct = 0; ct < 8; ct++) accT[ct] = (facc4){0.f,0.f,0.f,0.f};
  #pragma unroll
  for (int kc = 0; kc < 4; kc++){
    int kk = kc * 32 + kg * 8;
    int byteA = lr * 256 + kk * 2;
    bfrag8 a = *(const bfrag8*)(actL + (byteA ^ ((lr & 7) << 4)));
    #pragma unroll
    for (int ct = 0; ct < 8; ct++){
      int col = ct * 16 + rl;
      int byte = (col << 8) + (kk << 1);
      bfrag8 b = *(const bfrag8*)(lds + (byte ^ ((col & 7) << 4)));
      accT[ct] = __builtin_amdgcn_mfma_f32_16x16x32_bf16(a, b, accT[ct], 0, 0, 0);
    }
  }
  {
    const float* bias2 = f2b + i * HID_;
    #pragma unroll
    for (int ct = 0; ct < 8; ct++){
      int col = ct * 16 + rl;
      float bv2 = bias2[col];
      #pragma unroll
      for (int r = 0; r < 4; r++){
        int orow = rowBase + kg * 4 + r;
        if (orow < BM_){
          float tv = accT[ct][r] + bv2;
          float fw = 1.f / (1.f + expf(-tv));
          float u = accF[ct][r] * fw;
          u = u > 0.f ? u : 0.f;
          seg[(size_t)orow * (NSC_ * HID_) + i * HID_ + col] = f2bf(u);
        }
      }
    }
  }
}

// Fused classifier: logits = relu(seg @ W1 + b1) @ W2 + b2.
// Two 64KB phases for W1 (K=512), hid kept in acc -> LDS, in-block 128x20 dot.
__global__ __launch_bounds__(256) void k_cls(const unsigned short* __restrict__ seg,
    const unsigned short* __restrict__ c1T, const float* __restrict__ c1b,
    const unsigned short* __restrict__ c2T, const float* __restrict__ c2b,
    float* __restrict__ logits){
  __shared__ char lds[81920];
  char* actL = lds + 65536;
  const int lane = threadIdx.x & 63, wv = threadIdx.x >> 6;
  const int rl = lane & 15, kg = lane >> 4;
  const int rowBase = blockIdx.x * 64 + wv * 16;
  const int row = rowBase + rl;
  const bool rv = row < BM_;
  const unsigned short* ar = seg + (size_t)(rv ? row : 0) * 512;
  facc4 acc[8];
  #pragma unroll
  for (int ct = 0; ct < 8; ct++) acc[ct] = (facc4){0.f,0.f,0.f,0.f};
  for (int ph = 0; ph < 2; ph++){
    if (ph) __syncthreads();
    for (int c = threadIdx.x; c < 4096; c += 256){
      int byte = c << 4; int n = byte >> 9; int off = byte & 511;
      *(bfrag8*)(lds + (byte ^ ((n & 7) << 4))) =
          *(const bfrag8*)((const char*)c1T + (size_t)n * 1024 + ph * 512 + off);
    }
    __syncthreads();
    #pragma unroll
    for (int kc = 0; kc < 8; kc++){
      int kk = kc * 32 + kg * 8;
      bfrag8 a = (bfrag8){0,0,0,0,0,0,0,0};
      if (rv) a = *(const bfrag8*)(ar + ph * 256 + kk);
      #pragma unroll
      for (int ct = 0; ct < 8; ct++){
        int col = ct * 16 + rl;
        int byte = (col << 9) + (kk << 1);
        bfrag8 b = *(const bfrag8*)(lds + (byte ^ ((col & 7) << 4)));
        acc[ct] = __builtin_amdgcn_mfma_f32_16x16x32_bf16(a, b, acc[ct], 0, 0, 0);
      }
    }
  }
  __syncthreads();
  // relu(hid) -> act LDS; stage W2 bf16 [20][128] (5120B)
  #pragma unroll
  for (int ct = 0; ct < 8; ct++){
    int col = ct * 16 + rl;
    float bv = c1b[col];
    #pragma unroll
    for (int r = 0; r < 4; r++){
      int arr = wv * 16 + kg * 4 + r;
      float v = acc[ct][r] + bv; v = v > 0.f ? v : 0.f;
      int byte = arr * 256 + col * 2;
      *(unsigned short*)(actL + (byte ^ ((arr & 7) << 4))) = f2bf(v);
    }
  }
  for (int c = threadIdx.x; c < 320; c += 256)
    *(bfrag8*)(lds + (c << 4)) = *(const bfrag8*)((const char*)c2T + (c << 4));
  __syncthreads();
  // dot: thread -> (local row = t>>2, n-range = (t&3)*5 .. +5)
  {
    int t = threadIdx.x;
    int lrd = t >> 2, n0 = (t & 3) * 5;
    int orow = blockIdx.x * 64 + lrd;
    if (orow < BM_){
      float accD[5];
      #pragma unroll
      for (int q = 0; q < 5; q++) accD[q] = c2b[n0 + q];
      #pragma unroll
      for (int k8 = 0; k8 < 16; k8++){
        int byteA = lrd * 256 + (k8 << 4);
        bfrag8 hv = *(const bfrag8*)(actL + (byteA ^ ((lrd & 7) << 4)));
        #pragma unroll
        for (int q = 0; q < 5; q++){
          bfrag8 w8 = *(const bfrag8*)(lds + (n0 + q) * 256 + (k8 << 4));
          #pragma unroll
          for (int e = 0; e < 8; e++)
            accD[q] += bf2f((unsigned short)hv[e]) * bf2f((unsigned short)w8[e]);
        }
      }
      #pragma unroll
      for (int q = 0; q < 5; q++)
        logits[(size_t)orow * NCLS_ + n0 + q] = accD[q];
    }
  }
}

// ---------------------------------------------------------------------------
extern "C" void kernel_launch(void* const* d_in, const int* in_sizes, int n_in,
                              void* d_out, int out_size, void* d_ws, size_t ws_size,
                              hipStream_t stream){
  const float* samp = (const float*)d_in[1];   // pts_sample_feat (pts_feat_layers is dead)
  const float* img  = (const float*)d_in[2];
  const float* imgf = (const float*)d_in[3];
  const float* lW   = (const float*)d_in[4];
  const float* lb   = (const float*)d_in[5];
  const float* f1W  = (const float*)d_in[6];
  const float* f1b  = (const float*)d_in[7];
  const float* f2W  = (const float*)d_in[8];
  const float* f2b  = (const float*)d_in[9];
  const float* c1W  = (const float*)d_in[10];
  const float* c1b  = (const float*)d_in[11];
  const float* c2W  = (const float*)d_in[12];
  const float* c2b  = (const float*)d_in[13];
  const int* ptsimg = (const int*)d_in[14];
  const int* p2i    = (const int*)d_in[15];
  const int* si     = (const int*)d_in[16];
  const int* ci     = (const int*)d_in[17];

  char* ws = (char*)d_ws;
  int*   win_p = (int*)(ws + 0);                       //   960,000 B
  int*   win_s = (int*)(ws + 960000);                  //   960,000 B
  int*   win_c = (int*)(ws + 1920000);                 //   400,000 B
  int*   gidx  = (int*)(ws + 2320128);                 //   240,000 B
  unsigned short* iap = (unsigned short*)(ws + 2560256);    // 15,360,000 B
  unsigned short* seg = (unsigned short*)(ws + 17920384);   // 61,440,000 B
  unsigned short* lwT = (unsigned short*)(ws + 79360512);   // 131,072 B
  unsigned short* f1T = lwT + 65536;                        // 262,144 B
  unsigned short* f2T = f1T + 131072;                       // 131,072 B
  unsigned short* c1T = f2T + 65536;                        // 131,072 B
  unsigned short* c2T = c1T + 65536;                        //   5,120 B

  float* logits = (float*)d_out;
  float* o3d    = (float*)d_out + (size_t)BM_ * NCLS_;

  (void)hipMemsetAsync(ws, 0xFF, 2320000, stream);     // win_* = -1
  k_winners  <<<938,   256, 0, stream>>>(p2i, si, ci, win_p, win_s, win_c);
  k_imggather<<<30000, 256, 0, stream>>>(img, ptsimg, iap);
  k_gidx     <<<235,   256, 0, stream>>>(p2i, ci, win_c, gidx);
  k_prep     <<<1290,  256, 0, stream>>>(lW, f1W, f2W, c1W, c2W, lwT, f1T, f2T, c1T, c2T);
  k_out3d    <<<30000, 256, 0, stream>>>(samp, win_s, win_p, iap, o3d);
  for (int i = 0; i < NSC_; i++)
    k_scale<<<938, 256, 0, stream>>>(i, o3d, gidx, imgf, lwT, lb, f1T, f1b, f2T, f2b, seg);
  k_cls<<<938, 256, 0, stream>>>(seg, c1T, c1b, c2T, c2b, logits);
}

// Round 4
// 462.116 us; speedup vs baseline: 1.3752x; 1.2076x over previous
//
#include <hip/hip_runtime.h>
#include <hip/hip_bf16.h>
#include <math.h>

// Problem constants (fixed by the reference)
#define B_    2
#define N_    120000
#define S_    40000
#define M_    30000
#define V_    100000
#define H_    256
#define WD_   1024
#define HID_  128
#define NSC_  4
#define NCLS_ 20
#define BM_   60000    // B*M rows of the image branch
#define BS_   80000    // B*S sample rows
#define BN_   240000   // B*N point rows

typedef __attribute__((ext_vector_type(8))) short bfrag8;   // 8 bf16 (4 VGPRs) MFMA A/B frag
typedef __attribute__((ext_vector_type(4))) float facc4;    // 4 f32 MFMA C/D frag (native vec)
typedef __attribute__((ext_vector_type(4))) unsigned short usvec4;

__device__ __forceinline__ unsigned short f2bf(float f){
  unsigned u = __builtin_bit_cast(unsigned, f);
  u += 0x7fffu + ((u >> 16) & 1u);          // round-to-nearest-even
  return (unsigned short)(u >> 16);
}
__device__ __forceinline__ float bf2f(unsigned short s){
  return __builtin_bit_cast(float, ((unsigned)s) << 16);
}

// ---------------------------------------------------------------------------
// Winner scatters: last-wins == max index (np assignment semantics).
__global__ __launch_bounds__(256) void k_winners(const int* __restrict__ p2i,
    const int* __restrict__ si, const int* __restrict__ ci,
    int* __restrict__ win_p, int* __restrict__ win_s, int* __restrict__ win_c){
  int t = blockIdx.x * 256 + threadIdx.x;
  if (t < BM_) atomicMax(&win_p[(t / M_) * N_ + p2i[t]], t);
  if (t < BS_) atomicMax(&win_s[(t / S_) * N_ + si[t]], t);
  if (t < BN_) atomicMax(&win_c[ci[t]], t);
}

// g_idx[row] = win_c[ci[b*N + p2i[row]]]  (always >= 0: row itself scattered there)
__global__ __launch_bounds__(256) void k_gidx(const int* __restrict__ p2i,
    const int* __restrict__ ci, const int* __restrict__ win_c, int* __restrict__ gidx){
  int t = blockIdx.x * 256 + threadIdx.x;
  if (t >= BM_) return;
  int j = (t / M_) * N_ + p2i[t];
  gidx[t] = win_c[ci[j]];
}

// img_at_pts[row][h] = bf16(img_latent[b][h][r][c])  (scattered 4B reads)
__global__ __launch_bounds__(256) void k_imggather(const float* __restrict__ img,
    const int* __restrict__ ptsimg, unsigned short* __restrict__ iap){
  int t = blockIdx.x * 256 + threadIdx.x;       // t = row*128 + h, exact grid
  int row = t >> 7, h = t & 127;
  int b = row / M_;
  int r = ptsimg[row * 2 + 0];
  int c = ptsimg[row * 2 + 1];
  iap[t] = f2bf(img[(((size_t)b * HID_ + h) * H_ + r) * WD_ + c]);
}

// output_3d[j][i*128 + c] = samp_i[win_s[j]][c] + img_at_pts[win_p[j]][c]
__global__ __launch_bounds__(256) void k_out3d(const float* __restrict__ samp,
    const int* __restrict__ win_s, const int* __restrict__ win_p,
    const unsigned short* __restrict__ iap, float* __restrict__ o3d){
  int t = blockIdx.x * 256 + threadIdx.x;       // t = j*32 + q (float4 lane), exact grid
  int j = t >> 5, q = t & 31;
  int sj = win_s[j], pj = win_p[j];
  facc4 iv = {0.f, 0.f, 0.f, 0.f};
  if (pj >= 0){
    usvec4 u = __builtin_nontemporal_load((const usvec4*)(iap + (size_t)pj * HID_ + q * 4));
    iv.x = bf2f(u.x); iv.y = bf2f(u.y); iv.z = bf2f(u.z); iv.w = bf2f(u.w);
  }
  #pragma unroll
  for (int i = 0; i < NSC_; i++){
    facc4 v = iv;
    if (sj >= 0){
      facc4 s = __builtin_nontemporal_load((const facc4*)(samp + ((size_t)i * BS_ + sj) * HID_ + q * 4));
      v += s;
    }
    __builtin_nontemporal_store(v, (facc4*)(o3d + (size_t)j * (NSC_ * HID_) + i * HID_ + q * 4));
  }
}

// Pre-transpose all GEMM weights to bf16 [n][k] layout.
__global__ __launch_bounds__(256) void k_prep(const float* __restrict__ lW,
    const float* __restrict__ f1W, const float* __restrict__ f2W,
    const float* __restrict__ c1W, const float* __restrict__ c2W,
    unsigned short* __restrict__ lwT, unsigned short* __restrict__ f1T,
    unsigned short* __restrict__ f2T, unsigned short* __restrict__ c1T,
    unsigned short* __restrict__ c2T){
  int t = blockIdx.x * 256 + threadIdx.x;       // 330240 exact
  if (t < 65536){                                // leaner: 4 x [128][128]
    int i = t >> 14, r = t & 16383, n = r >> 7, k = r & 127;
    lwT[i * 16384 + n * 128 + k] = f2bf(lW[i * 16384 + k * 128 + n]);
  } else if (t < 196608){                        // fcs1: 4 x [128][256]
    int e = t - 65536;
    int i = e >> 15, r = e & 32767, n = r >> 8, k = r & 255;
    f1T[i * 32768 + n * 256 + k] = f2bf(f1W[i * 32768 + k * 128 + n]);
  } else if (t < 262144){                        // fcs2: 4 x [128][128]
    int e = t - 196608;
    int i = e >> 14, r = e & 16383, n = r >> 7, k = r & 127;
    f2T[i * 16384 + n * 128 + k] = f2bf(f2W[i * 16384 + k * 128 + n]);
  } else if (t < 327680){                        // cls_W1: [128][512]
    int e = t - 262144;
    int n = e >> 9, k = e & 511;
    c1T[n * 512 + k] = f2bf(c1W[k * 128 + n]);
  } else if (t < 330240){                        // cls_W2: [20][128]
    int e = t - 327680;
    int n = e >> 7, k = e & 127;
    c2T[n * 128 + k] = f2bf(c2W[k * NCLS_ + n]);
  }
}

// ---------------------------------------------------------------------------
// Merged per-scale MLP over ALL 4 scales (independent): i = blockIdx.x & 3.
// seg[:, i*128:(i+1)*128] = relu(fc * sigmoid(fc @ W2 + b2)),
//   fc = [imgf_i | relu(spG @ Wl + bl)] @ W1 + b1
// Block = 256 thr (4 waves), 64 rows. LDS 48KB: 32KB weight buf (fcs1 staged as
// two K-halves, split exactly at the concat boundary) + 16KB act buf.
// 3 blocks/CU, 12 waves/CU.
__global__ __launch_bounds__(256, 3) void k_scales(
    const float* __restrict__ o3d, const int* __restrict__ gidx,
    const float* __restrict__ imgf,
    const unsigned short* __restrict__ lwT, const float* __restrict__ lb,
    const unsigned short* __restrict__ f1T, const float* __restrict__ f1b,
    const unsigned short* __restrict__ f2T, const float* __restrict__ f2b,
    unsigned short* __restrict__ seg){
  __shared__ char lds[49152];
  char* actL = lds + 32768;
  const int i  = blockIdx.x & 3;
  const int rb = blockIdx.x >> 2;
  const int lane = threadIdx.x & 63, wv = threadIdx.x >> 6;
  const int rl = lane & 15, kg = lane >> 4;
  const int rowBase = rb * 64 + wv * 16;
  const int row = rowBase + rl;                 // this lane's A row
  const bool rv = row < BM_;
  const int lr = wv * 16 + rl;                  // block-local A row

  // ---- stage leaner W [128n][128k] (32KB) ----
  {
    const char* src = (const char*)(lwT + (size_t)i * 16384);
    for (int c = threadIdx.x; c < 2048; c += 256){
      int byte = c << 4; int n = byte >> 8;
      *(bfrag8*)(lds + (byte ^ ((n & 7) << 4))) = *(const bfrag8*)(src + byte);
    }
  }
  // A frags for leaner: gathered o3d row (= sp for this scale)
  bfrag8 afr[4];
  {
    const float* aA = o3d + (size_t)(rv ? gidx[row] : 0) * (NSC_ * HID_) + i * HID_;
    #pragma unroll
    for (int kc = 0; kc < 4; kc++){
      int k0 = kc * 32 + kg * 8;
      facc4 s0 = {0,0,0,0}, s1 = {0,0,0,0};
      if (rv){ s0 = *(const facc4*)(aA + k0); s1 = *(const facc4*)(aA + k0 + 4); }
      bfrag8 a;
      a[0]=(short)f2bf(s0.x); a[1]=(short)f2bf(s0.y); a[2]=(short)f2bf(s0.z); a[3]=(short)f2bf(s0.w);
      a[4]=(short)f2bf(s1.x); a[5]=(short)f2bf(s1.y); a[6]=(short)f2bf(s1.z); a[7]=(short)f2bf(s1.w);
      afr[kc] = a;
    }
  }
  __syncthreads();
  // ---- Phase A: leaner MFMA ----
  facc4 accL[8];
  #pragma unroll
  for (int ct = 0; ct < 8; ct++) accL[ct] = (facc4){0.f,0.f,0.f,0.f};
  #pragma unroll
  for (int kc = 0; kc < 4; kc++){
    int k0 = kc * 32 + kg * 8;
    #pragma unroll
    for (int ct = 0; ct < 8; ct++){
      int col = ct * 16 + rl;
      int byte = (col << 8) + (k0 << 1);
      bfrag8 b = *(const bfrag8*)(lds + (byte ^ ((col & 7) << 4)));
      accL[ct] = __builtin_amdgcn_mfma_f32_16x16x32_bf16(afr[kc], b, accL[ct], 0, 0, 0);
    }
  }
  __syncthreads();                               // lW reads done
  // fl -> act LDS (bf16, relu); stage fcs1 K-half 0 (imgf part)
  {
    const float* bias = lb + i * HID_;
    #pragma unroll
    for (int ct = 0; ct < 8; ct++){
      int col = ct * 16 + rl;
      float bv = bias[col];
      #pragma unroll
      for (int r = 0; r < 4; r++){
        int ar = wv * 16 + kg * 4 + r;
        float v = accL[ct][r] + bv; v = v > 0.f ? v : 0.f;
        int byte = ar * 256 + col * 2;
        *(unsigned short*)(actL + (byte ^ ((ar & 7) << 4))) = f2bf(v);
      }
    }
    const char* src = (const char*)(f1T + (size_t)i * 32768);
    for (int c = threadIdx.x; c < 2048; c += 256){
      int n = c >> 4, off = (c & 15) << 4;
      *(bfrag8*)(lds + ((n * 256 + off) ^ ((n & 7) << 4))) =
          *(const bfrag8*)(src + (size_t)n * 512 + off);
    }
  }
  __syncthreads();
  // ---- Phase B1: fcs1, k in [0,128) — A = imgf (global) ----
  facc4 accF[8];
  #pragma unroll
  for (int ct = 0; ct < 8; ct++) accF[ct] = (facc4){0.f,0.f,0.f,0.f};
  {
    const float* a1 = imgf + ((size_t)i * BM_ + (rv ? row : 0)) * HID_;
    #pragma unroll
    for (int kc = 0; kc < 4; kc++){
      int kk = kc * 32 + kg * 8;
      bfrag8 a = (bfrag8){0,0,0,0,0,0,0,0};
      if (rv){
        facc4 s0 = *(const facc4*)(a1 + kk);
        facc4 s1 = *(const facc4*)(a1 + kk + 4);
        a[0]=(short)f2bf(s0.x); a[1]=(short)f2bf(s0.y); a[2]=(short)f2bf(s0.z); a[3]=(short)f2bf(s0.w);
        a[4]=(short)f2bf(s1.x); a[5]=(short)f2bf(s1.y); a[6]=(short)f2bf(s1.z); a[7]=(short)f2bf(s1.w);
      }
      #pragma unroll
      for (int ct = 0; ct < 8; ct++){
        int col = ct * 16 + rl;
        int byte = (col << 8) + (kk << 1);
        bfrag8 b = *(const bfrag8*)(lds + (byte ^ ((col & 7) << 4)));
        accF[ct] = __builtin_amdgcn_mfma_f32_16x16x32_bf16(a, b, accF[ct], 0, 0, 0);
      }
    }
  }
  __syncthreads();                               // f1-half0 reads done
  // stage fcs1 K-half 1 (fl part)
  {
    const char* src = (const char*)(f1T + (size_t)i * 32768) + 256;
    for (int c = threadIdx.x; c < 2048; c += 256){
      int n = c >> 4, off = (c & 15) << 4;
      *(bfrag8*)(lds + ((n * 256 + off) ^ ((n & 7) << 4))) =
          *(const bfrag8*)(src + (size_t)n * 512 + off);
    }
  }
  __syncthreads();
  // ---- Phase B2: fcs1, k in [128,256) — A = fl (act LDS) ----
  #pragma unroll
  for (int kc = 0; kc < 4; kc++){
    int kl = kc * 32 + kg * 8;
    int byteA = lr * 256 + kl * 2;
    bfrag8 a = *(const bfrag8*)(actL + (byteA ^ ((lr & 7) << 4)));
    #pragma unroll
    for (int ct = 0; ct < 8; ct++){
      int col = ct * 16 + rl;
      int byte = (col << 8) + (kl << 1);
      bfrag8 b = *(const bfrag8*)(lds + (byte ^ ((col & 7) << 4)));
      accF[ct] = __builtin_amdgcn_mfma_f32_16x16x32_bf16(a, b, accF[ct], 0, 0, 0);
    }
  }
  __syncthreads();                               // act(fl) + f1-half1 reads done
  // fc (+bias, kept f32 in accF) -> act LDS; stage fcs2 W
  {
    const float* bias = f1b + i * HID_;
    #pragma unroll
    for (int ct = 0; ct < 8; ct++){
      int col = ct * 16 + rl;
      float bv = bias[col];
      #pragma unroll
      for (int r = 0; r < 4; r++){
        int ar = wv * 16 + kg * 4 + r;
        float v = accF[ct][r] + bv;
        accF[ct][r] = v;
        int byte = ar * 256 + col * 2;
        *(unsigned short*)(actL + (byte ^ ((ar & 7) << 4))) = f2bf(v);
      }
    }
    const char* src = (const char*)(f2T + (size_t)i * 16384);
    for (int c = threadIdx.x; c < 2048; c += 256){
      int byte = c << 4; int n = byte >> 8;
      *(bfrag8*)(lds + (byte ^ ((n & 7) << 4))) = *(const bfrag8*)(src + byte);
    }
  }
  __syncthreads();
  // ---- Phase C: fcs2 + gate epilogue ----
  facc4 accT[8];
  #pragma unroll
  for (int ct = 0; ct < 8; ct++) accT[ct] = (facc4){0.f,0.f,0.f,0.f};
  #pragma unroll
  for (int kc = 0; kc < 4; kc++){
    int kk = kc * 32 + kg * 8;
    int byteA = lr * 256 + kk * 2;
    bfrag8 a = *(const bfrag8*)(actL + (byteA ^ ((lr & 7) << 4)));
    #pragma unroll
    for (int ct = 0; ct < 8; ct++){
      int col = ct * 16 + rl;
      int byte = (col << 8) + (kk << 1);
      bfrag8 b = *(const bfrag8*)(lds + (byte ^ ((col & 7) << 4)));
      accT[ct] = __builtin_amdgcn_mfma_f32_16x16x32_bf16(a, b, accT[ct], 0, 0, 0);
    }
  }
  {
    const float* bias2 = f2b + i * HID_;
    #pragma unroll
    for (int ct = 0; ct < 8; ct++){
      int col = ct * 16 + rl;
      float bv2 = bias2[col];
      #pragma unroll
      for (int r = 0; r < 4; r++){
        int orow = rowBase + kg * 4 + r;
        if (orow < BM_){
          float tv = accT[ct][r] + bv2;
          float fw = 1.f / (1.f + expf(-tv));
          float u = accF[ct][r] * fw;
          u = u > 0.f ? u : 0.f;
          seg[(size_t)orow * (NSC_ * HID_) + i * HID_ + col] = f2bf(u);
        }
      }
    }
  }
}

// Fused classifier: logits = relu(seg @ W1 + b1) @ W2 + b2.
// W1 staged as 4 x 32KB K-quarters; 48KB LDS, 3 blocks/CU.
__global__ __launch_bounds__(256, 3) void k_cls(const unsigned short* __restrict__ seg,
    const unsigned short* __restrict__ c1T, const float* __restrict__ c1b,
    const unsigned short* __restrict__ c2T, const float* __restrict__ c2b,
    float* __restrict__ logits){
  __shared__ char lds[49152];
  char* actL = lds + 32768;
  const int lane = threadIdx.x & 63, wv = threadIdx.x >> 6;
  const int rl = lane & 15, kg = lane >> 4;
  const int rowBase = blockIdx.x * 64 + wv * 16;
  const int row = rowBase + rl;
  const bool rv = row < BM_;
  const unsigned short* ar = seg + (size_t)(rv ? row : 0) * 512;
  facc4 acc[8];
  #pragma unroll
  for (int ct = 0; ct < 8; ct++) acc[ct] = (facc4){0.f,0.f,0.f,0.f};
  for (int ph = 0; ph < 4; ph++){
    if (ph) __syncthreads();
    for (int c = threadIdx.x; c < 2048; c += 256){
      int n = c >> 4, off = (c & 15) << 4;
      *(bfrag8*)(lds + ((n * 256 + off) ^ ((n & 7) << 4))) =
          *(const bfrag8*)((const char*)c1T + (size_t)n * 1024 + ph * 256 + off);
    }
    __syncthreads();
    #pragma unroll
    for (int kc = 0; kc < 4; kc++){
      int kl = kc * 32 + kg * 8;
      bfrag8 a = (bfrag8){0,0,0,0,0,0,0,0};
      if (rv) a = *(const bfrag8*)(ar + ph * 128 + kl);
      #pragma unroll
      for (int ct = 0; ct < 8; ct++){
        int col = ct * 16 + rl;
        int byte = (col << 8) + (kl << 1);
        bfrag8 b = *(const bfrag8*)(lds + (byte ^ ((col & 7) << 4)));
        acc[ct] = __builtin_amdgcn_mfma_f32_16x16x32_bf16(a, b, acc[ct], 0, 0, 0);
      }
    }
  }
  __syncthreads();
  // relu(hid) -> act LDS; stage W2 bf16 [20][128] (5120B at lds+0)
  #pragma unroll
  for (int ct = 0; ct < 8; ct++){
    int col = ct * 16 + rl;
    float bv = c1b[col];
    #pragma unroll
    for (int r = 0; r < 4; r++){
      int arr = wv * 16 + kg * 4 + r;
      float v = acc[ct][r] + bv; v = v > 0.f ? v : 0.f;
      int byte = arr * 256 + col * 2;
      *(unsigned short*)(actL + (byte ^ ((arr & 7) << 4))) = f2bf(v);
    }
  }
  for (int c = threadIdx.x; c < 320; c += 256)
    *(bfrag8*)(lds + (c << 4)) = *(const bfrag8*)((const char*)c2T + (c << 4));
  __syncthreads();
  // dot: thread -> (local row = t>>2, n-range = (t&3)*5 .. +5)
  {
    int t = threadIdx.x;
    int lrd = t >> 2, n0 = (t & 3) * 5;
    int orow = blockIdx.x * 64 + lrd;
    if (orow < BM_){
      float accD[5];
      #pragma unroll
      for (int q = 0; q < 5; q++) accD[q] = c2b[n0 + q];
      #pragma unroll
      for (int k8 = 0; k8 < 16; k8++){
        int byteA = lrd * 256 + (k8 << 4);
        bfrag8 hv = *(const bfrag8*)(actL + (byteA ^ ((lrd & 7) << 4)));
        #pragma unroll
        for (int q = 0; q < 5; q++){
          bfrag8 w8 = *(const bfrag8*)(lds + (n0 + q) * 256 + (k8 << 4));
          #pragma unroll
          for (int e = 0; e < 8; e++)
            accD[q] += bf2f((unsigned short)hv[e]) * bf2f((unsigned short)w8[e]);
        }
      }
      #pragma unroll
      for (int q = 0; q < 5; q++)
        logits[(size_t)orow * NCLS_ + n0 + q] = accD[q];
    }
  }
}

// ---------------------------------------------------------------------------
extern "C" void kernel_launch(void* const* d_in, const int* in_sizes, int n_in,
                              void* d_out, int out_size, void* d_ws, size_t ws_size,
                              hipStream_t stream){
  const float* samp = (const float*)d_in[1];   // pts_sample_feat (pts_feat_layers is dead)
  const float* img  = (const float*)d_in[2];
  const float* imgf = (const float*)d_in[3];
  const float* lW   = (const float*)d_in[4];
  const float* lb   = (const float*)d_in[5];
  const float* f1W  = (const float*)d_in[6];
  const float* f1b  = (const float*)d_in[7];
  const float* f2W  = (const float*)d_in[8];
  const float* f2b  = (const float*)d_in[9];
  const float* c1W  = (const float*)d_in[10];
  const float* c1b  = (const float*)d_in[11];
  const float* c2W  = (const float*)d_in[12];
  const float* c2b  = (const float*)d_in[13];
  const int* ptsimg = (const int*)d_in[14];
  const int* p2i    = (const int*)d_in[15];
  const int* si     = (const int*)d_in[16];
  const int* ci     = (const int*)d_in[17];

  char* ws = (char*)d_ws;
  int*   win_p = (int*)(ws + 0);                       //   960,000 B
  int*   win_s = (int*)(ws + 960000);                  //   960,000 B
  int*   win_c = (int*)(ws + 1920000);                 //   400,000 B
  int*   gidx  = (int*)(ws + 2320128);                 //   240,000 B
  unsigned short* iap = (unsigned short*)(ws + 2560256);    // 15,360,000 B
  unsigned short* seg = (unsigned short*)(ws + 17920384);   // 61,440,000 B
  unsigned short* lwT = (unsigned short*)(ws + 79360512);   // 131,072 B
  unsigned short* f1T = lwT + 65536;                        // 262,144 B
  unsigned short* f2T = f1T + 131072;                       // 131,072 B
  unsigned short* c1T = f2T + 65536;                        // 131,072 B
  unsigned short* c2T = c1T + 65536;                        //   5,120 B

  float* logits = (float*)d_out;
  float* o3d    = (float*)d_out + (size_t)BM_ * NCLS_;

  (void)hipMemsetAsync(ws, 0xFF, 2320000, stream);     // win_* = -1
  k_winners  <<<938,   256, 0, stream>>>(p2i, si, ci, win_p, win_s, win_c);
  k_imggather<<<30000, 256, 0, stream>>>(img, ptsimg, iap);
  k_gidx     <<<235,   256, 0, stream>>>(p2i, ci, win_c, gidx);
  k_prep     <<<1290,  256, 0, stream>>>(lW, f1W, f2W, c1W, c2W, lwT, f1T, f2T, c1T, c2T);
  k_out3d    <<<30000, 256, 0, stream>>>(samp, win_s, win_p, iap, o3d);
  k_scales   <<<3752,  256, 0, stream>>>(o3d, gidx, imgf, lwT, lb, f1T, f1b, f2T, f2b, seg);
  k_cls      <<<938,   256, 0, stream>>>(seg, c1T, c1b, c2T, c2b, logits);
}